// Round 19
// baseline (623.012 us; speedup 1.0000x reference)
//
#include <hip/hip_runtime.h>

typedef unsigned long long u64;
typedef unsigned int u32;
typedef unsigned short u16;

#define N_ROWS 16384
#define DIM    512
#define K_CODES 8192

#define CHUNKS 64
#define CHUNK_CODES 128
#define BMR 256              // x-rows per block
#define KC 32
#define KTILES (DIM / KC)    // 16

typedef short bf16x8 __attribute__((ext_vector_type(8)));
typedef float f32x4  __attribute__((ext_vector_type(4)));

// sorted ascending 2-slot insert (verified r5-r18)
__device__ __forceinline__ void t2_insert(u64* a, u64 k) {
    u64 lo = a[0], hi = a[1];
    bool lt0 = k < lo;
    u64 n1k = (k < hi) ? k : hi;
    a[0] = lt0 ? k : lo;
    a[1] = lt0 ? lo : n1k;
}

// ---------------- Kernel P: precompute bf16 HI-plane split only (verified r14-r18) ----
__global__ void vq_split_kernel(const float* __restrict__ x, const float* __restrict__ cb,
                                u16* __restrict__ xhi, u16* __restrict__ cbhi) {
    size_t t = (size_t)blockIdx.x * blockDim.x + threadIdx.x;
    const size_t nx = (size_t)N_ROWS * DIM / 4;
    const size_t nc = (size_t)K_CODES * DIM / 4;
    const float4* src;
    u16* hi;
    size_t off;
    if (t < nx)            { src = (const float4*)x;  hi = xhi;  off = t; }
    else if (t < nx + nc)  { src = (const float4*)cb; hi = cbhi; off = t - nx; }
    else return;
    float4 v = src[off];
    u16 h0 = (u16)(__float_as_uint(v.x) >> 16);
    u16 h1 = (u16)(__float_as_uint(v.y) >> 16);
    u16 h2 = (u16)(__float_as_uint(v.z) >> 16);
    u16 h3 = (u16)(__float_as_uint(v.w) >> 16);
    ((ushort4*)hi)[off] = make_ushort4(h0, h1, h2, h3);
}

// ---------------- Kernel N: numpy-pairwise fp32 row norms, wave-parallel (verified r18) ----
__global__ void vq_np_norm_kernel(const float* __restrict__ x, const float* __restrict__ cb,
                                  float* __restrict__ Arow, float* __restrict__ Bcode) {
    int wid = (blockIdx.x * blockDim.x + threadIdx.x) >> 6;
    int lane = threadIdx.x & 63;
    int r2 = lane >> 5;          // row within the wave's pair
    int b  = (lane >> 3) & 3;    // 128-block index
    int j  = lane & 7;           // accumulator index
    int row = wid * 2 + r2;
    const float* p;
    float* o;
    if (row < N_ROWS) { p = x + (size_t)row * DIM; o = Arow + row; }
    else              { int c = row - N_ROWS; p = cb + (size_t)c * DIM; o = Bcode + c; }
    const float* q = p + b * 128 + j;
    float v0 = q[0];
    float s = __fmul_rn(v0, v0);
    #pragma unroll
    for (int i = 1; i < 16; ++i) {
        float v = q[8 * i];
        s = __fadd_rn(s, __fmul_rn(v, v));
    }
    s = __fadd_rn(s, __shfl_xor(s, 1));
    s = __fadd_rn(s, __shfl_xor(s, 2));
    s = __fadd_rn(s, __shfl_xor(s, 4));
    s = __fadd_rn(s, __shfl_xor(s, 8));
    s = __fadd_rn(s, __shfl_xor(s, 16));
    if ((lane & 31) == 0) *o = s;
}

// ---------------- Kernel S: hh-only MFMA screen, 64x128 wave tiles, 3 blocks/CU ------
// Identical to r18 (verified) except __launch_bounds__(256,3): measured VGPR=120
// fits the 170-reg budget; LDS 3x48KB = 144 <= 160KB. Third co-resident block
// restores the cross-block desync overlap (r17's 3-block pattern) at r18's
// MFMA-dominant intensity (12 ds_read_b128 -> 32 MFMA per wave-tile).
__launch_bounds__(256, 3)
__global__ void vq_screen_kernel(const u16* __restrict__ xhi, const u16* __restrict__ cbhi,
                                 u64* __restrict__ top2out) {
    __shared__ __align__(16) u16 lds[2][12288];   // 2 x 24KB: X[256][32] @0 | C[128][32] @8192

    const int t = threadIdx.x;
    const int lane = t & 63;
    const int w = t >> 6;        // 0..3
    const int wrow  = w >> 1;    // 0..1 -> x-rows [128*wrow, +128)
    const int wcode = w & 1;     // 0..1 -> codes  [64*wcode, +64)
    const int r15 = lane & 15;
    const int g = lane >> 4;     // 0..3
    const int cswz = (r15 >> 1) & 3;

    const int rowBase   = blockIdx.x * BMR;
    const int chunkBase = blockIdx.y * CHUNK_CODES;

    const size_t laneOff = (size_t)(lane >> 2) * DIM
                         + (size_t)(((lane & 3) ^ ((lane >> 3) & 3)) * 8);

    // 6 staging segments per wave: q = j*4 + w over [X groups 0-15 | C groups 16-23]
    const u16* srcs[6];
    int dsts[6];
    #pragma unroll
    for (int j = 0; j < 6; ++j) {
        int q = j * 4 + w;
        const u16* gp = (q < 16) ? (xhi + (size_t)(rowBase + q * 16) * DIM)
                                 : (cbhi + (size_t)(chunkBase + (q - 16) * 16) * DIM);
        srcs[j] = gp + laneOff;
        dsts[j] = q * 512;
    }

    auto stage = [&](int kt, int b) {
        #pragma unroll
        for (int j = 0; j < 6; ++j) {
            __builtin_amdgcn_global_load_lds(
                (const __attribute__((address_space(1))) u32*)(srcs[j] + kt * KC),
                (__attribute__((address_space(3))) u32*)(&lds[b][dsts[j]]),
                16, 0, 0);
        }
    };

    f32x4 acc[4][8] = {};   // [mi = code frag][ni = x-row frag]

    stage(0, 0);

    #pragma unroll
    for (int kt = 0; kt < KTILES; ++kt) {
        if (kt + 1 < KTILES) {
            stage(kt + 1, (kt + 1) & 1);
            asm volatile("s_waitcnt vmcnt(6)" ::: "memory");
        } else {
            asm volatile("s_waitcnt vmcnt(0)" ::: "memory");
        }
        asm volatile("s_barrier" ::: "memory");

        const u16* L = &lds[kt & 1][0];
        bf16x8 Cf[4], Xf[8];
        #pragma unroll
        for (int mi = 0; mi < 4; ++mi)
            Cf[mi] = *(const bf16x8*)&L[8192 + (wcode * 64 + mi * 16 + r15) * 32 + (g ^ cswz) * 8];
        #pragma unroll
        for (int ni = 0; ni < 8; ++ni)
            Xf[ni] = *(const bf16x8*)&L[(wrow * 128 + ni * 16 + r15) * 32 + (g ^ cswz) * 8];
        __builtin_amdgcn_s_setprio(1);
        #pragma unroll
        for (int ni = 0; ni < 8; ++ni)
            #pragma unroll
            for (int mi = 0; mi < 4; ++mi)
                acc[mi][ni] = __builtin_amdgcn_mfma_f32_16x16x32_bf16(Cf[mi], Xf[ni], acc[mi][ni], 0, 0, 0);
        __builtin_amdgcn_s_setprio(0);
        asm volatile("s_barrier" ::: "memory");
    }

    // ---- fold: per x-row, top-2 MAX of raw dot over this lane's 16 codes ----
    __syncthreads();
    u64* t2buf = (u64*)&lds[0][0];   // [256 rows][2 wcode][2 slots] = 8KB

    #pragma unroll
    for (int ni = 0; ni < 8; ++ni) {
        const int xrow = wrow * 128 + ni * 16 + r15;
        float v0 = -3.4e38f, v1 = -3.4e38f;
        int   i0 = 0, i1 = 0;
        #pragma unroll
        for (int mi = 0; mi < 4; ++mi) {
            const int colBase = chunkBase + wcode * 64 + mi * 16 + g * 4;
            #pragma unroll
            for (int reg = 0; reg < 4; ++reg) {
                float v = acc[mi][ni][reg];
                int idx = colBase + reg;
                bool c0 = v > v0;
                bool c1 = v > v1;
                v1 = c0 ? v0 : (c1 ? v : v1);
                i1 = c0 ? i0 : (c1 ? idx : i1);
                v0 = c0 ? v : v0;
                i0 = c0 ? idx : i0;
            }
        }
        // merge across the 4 g-lanes (xor 16, 32); 16 rows merged in parallel
        #pragma unroll
        for (int m = 16; m <= 32; m <<= 1) {
            float ov0 = __shfl_xor(v0, m), ov1 = __shfl_xor(v1, m);
            int   oi0 = __shfl_xor(i0, m), oi1 = __shfl_xor(i1, m);
            bool aw = (v0 > ov0) || (v0 == ov0 && i0 < oi0);
            float wt = aw ? v0 : ov0;   int wi = aw ? i0 : oi0;
            float lt2 = aw ? ov0 : v0;  int li = aw ? oi0 : i0;
            float ws2 = aw ? v1 : ov1;  int si = aw ? i1 : oi1;
            bool sw = (lt2 > ws2) || (lt2 == ws2 && li < si);
            v0 = wt; i0 = wi;
            v1 = sw ? lt2 : ws2; i1 = sw ? li : si;
        }
        if (g == 0) {
            // monotonic map: descending dot -> ascending u32
            u32 s0 = __float_as_uint(v0);
            u32 km0 = (v0 < 0.0f) ? s0 : (~s0 & 0x7FFFFFFFu);
            u32 s1 = __float_as_uint(v1);
            u32 km1 = (v1 < 0.0f) ? s1 : (~s1 & 0x7FFFFFFFu);
            t2buf[(xrow * 2 + wcode) * 2 + 0] = ((u64)km0 << 13) | (u32)i0;
            t2buf[(xrow * 2 + wcode) * 2 + 1] = ((u64)km1 << 13) | (u32)i1;
        }
    }
    __syncthreads();
    if (t < BMR) {
        u64 best[2];
        best[0] = t2buf[(t * 2 + 0) * 2 + 0];
        best[1] = t2buf[(t * 2 + 0) * 2 + 1];
        t2_insert(best, t2buf[(t * 2 + 1) * 2 + 0]);
        t2_insert(best, t2buf[(t * 2 + 1) * 2 + 1]);
        size_t o = ((size_t)blockIdx.y * N_ROWS + rowBase + t) * 2;
        top2out[o + 0] = best[0];
        top2out[o + 1] = best[1];
    }
}

// ---------------- Kernel R: global top-8 of 64x2 keys -> exact np re-decision --------
__global__ void vq_refine_kernel(const float* __restrict__ x, const float* __restrict__ cb,
                                 const float* __restrict__ Arow, const float* __restrict__ Bcode,
                                 const u64* __restrict__ top2, int* __restrict__ idxOut,
                                 float* __restrict__ out4) {
    int gw = (blockIdx.x * blockDim.x + threadIdx.x) >> 6;
    int lane = threadIdx.x & 63;
    if (gw >= N_ROWS) return;

    const u64* tp = top2 + ((size_t)lane * N_ROWS + gw) * 2;
    u64 a0 = tp[0], a1 = tp[1];

    u64 cand[8];
    #pragma unroll
    for (int j = 0; j < 8; ++j) {
        u64 m = a0;
        #pragma unroll
        for (int s = 1; s < 64; s <<= 1) { u64 o = __shfl_xor(m, s); m = o < m ? o : m; }
        cand[j] = m;
        if (a0 == m) { a0 = a1; a1 = ~0ull; }
    }

    float Ai = Arow[gw];
    const float* xr = x + (size_t)gw * DIM;
    float xv[8];
    #pragma unroll
    for (int e = 0; e < 8; ++e) xv[e] = xr[e * 64 + lane];

    u64 best = ~0ull;
    #pragma unroll
    for (int j = 0; j < 8; ++j) {
        int c = (int)(cand[j] & 8191u);
        const float* er = cb + (size_t)c * DIM;
        double d = 0.0;
        #pragma unroll
        for (int e = 0; e < 8; ++e)
            d = fma((double)xv[e], (double)er[e * 64 + lane], d);
        #pragma unroll
        for (int m = 1; m < 64; m <<= 1) d += __shfl_xor(d, m);
        float m32 = (float)d;
        float dist = __fsub_rn(__fadd_rn(Ai, Bcode[c]), 2.0f * m32);
        u64 ek = ((u64)__float_as_uint(dist) << 13) | (u64)(u32)c;
        best = ek < best ? ek : best;
    }
    if (lane == 0) {
        int c = (int)(best & 8191u);
        idxOut[gw] = c;
        out4[gw] = (float)c;
    }
}

// ---------------- Kernel C: gather + outputs + per-row loss partial ----------------
__global__ void vq_gather_kernel(const float* __restrict__ x,
                                 const float* __restrict__ cb,
                                 const int* __restrict__ idxArr,
                                 float* __restrict__ out0,
                                 float* __restrict__ out3,
                                 float* __restrict__ rowPart) {
    int gw = (blockIdx.x * blockDim.x + threadIdx.x) >> 6;
    int lane = threadIdx.x & 63;
    if (gw >= N_ROWS) return;
    int idx = idxArr[gw];
    const float2* xp = (const float2*)(x  + (size_t)gw * DIM);
    const float2* qp = (const float2*)(cb + (size_t)idx * DIM);
    float2* o0 = (float2*)(out0 + (size_t)gw * DIM);
    float2* o3 = (float2*)(out3 + (size_t)gw * DIM);
    float part = 0.0f;
    #pragma unroll
    for (int r = 0; r < 4; ++r) {
        int e = r * 64 + lane;
        float2 xv = xp[e];
        float2 qv = qp[e];
        float dx = qv.x - xv.x, dy = qv.y - xv.y;
        part += dx * dx + dy * dy;
        float2 o; o.x = xv.x + dx; o.y = xv.y + dy;
        o0[e] = o;
        o3[e] = qv;
    }
    #pragma unroll
    for (int m = 32; m; m >>= 1) part += __shfl_xor(part, m);
    if (lane == 0) rowPart[gw] = part;
}

// ---------------- Kernel D: deterministic loss reduce ----------------
__global__ void vq_loss_kernel(const float* __restrict__ rowPart,
                               float* __restrict__ out1, float* __restrict__ out2) {
    __shared__ float red[256];
    int t = threadIdx.x;
    float s = 0.0f;
    for (int r = t; r < N_ROWS; r += 256) s += rowPart[r];
    red[t] = s;
    __syncthreads();
    #pragma unroll
    for (int m = 128; m; m >>= 1) {
        if (t < m) red[t] += red[t + m];
        __syncthreads();
    }
    if (t == 0) {
        float loss = red[0] / (float)(N_ROWS * DIM);
        out1[0] = loss;
        out2[0] = loss;
    }
}

extern "C" void kernel_launch(void* const* d_in, const int* in_sizes, int n_in,
                              void* d_out, int out_size, void* d_ws, size_t ws_size,
                              hipStream_t stream) {
    const float* x  = (const float*)d_in[0];   // [16384, 512]
    const float* cb = (const float*)d_in[1];   // [8192, 512]
    float* out  = (float*)d_out;
    float* out0 = out;                         // quantized_out [8388608]
    float* out1 = out + 8388608;               // q_latent_loss [1]
    float* out2 = out + 8388609;               // e_latent_loss [1]
    float* out3 = out + 8388610;               // quantized [8388608]
    float* out4 = out + 16777218;              // idx as float [16384]

    // d_out scratch (stream-ordered; consumed before gather overwrites):
    // xhi 16.8MB + cbhi 8.4MB in out0 region; top2 (64*16384*2 u64 = 16.8MB) in out3 region.
    u16* xhi    = (u16*)out0;                  // [0, 4194304) floats
    u16* cbhi   = (u16*)(out + 4194304);       // [4194304, 6291456)
    u64* wsTop2 = (u64*)(out + 8388612);       // [8388612, 12582916)  8B-aligned

    char* ws = (char*)d_ws;
    float* wsA    = (float*)ws;                // 16384 f
    float* wsB    = (float*)(ws + 65536);      // 8192 f
    int*   wsIdx  = (int*)(ws + 98304);        // 16384 int
    float* wsPart = (float*)(ws + 163840);     // 16384 f

    hipLaunchKernelGGL(vq_split_kernel,   dim3(12288), dim3(256), 0, stream,
                       x, cb, xhi, cbhi);
    hipLaunchKernelGGL(vq_np_norm_kernel, dim3(3072), dim3(256), 0, stream, x, cb, wsA, wsB);
    hipLaunchKernelGGL(vq_screen_kernel,  dim3(N_ROWS / BMR, CHUNKS), dim3(256), 0, stream,
                       xhi, cbhi, wsTop2);
    hipLaunchKernelGGL(vq_refine_kernel,  dim3(4096), dim3(256), 0, stream,
                       x, cb, wsA, wsB, wsTop2, wsIdx, out4);
    hipLaunchKernelGGL(vq_gather_kernel,  dim3(4096), dim3(256), 0, stream,
                       x, cb, wsIdx, out0, out3, wsPart);
    hipLaunchKernelGGL(vq_loss_kernel,    dim3(1),   dim3(256), 0, stream,
                       wsPart, out1, out2);
}

// Round 20
// 261.236 us; speedup vs baseline: 2.3849x; 2.3849x over previous
//
#include <hip/hip_runtime.h>

typedef unsigned long long u64;
typedef unsigned int u32;
typedef unsigned short u16;

#define N_ROWS 16384
#define DIM    512
#define K_CODES 8192

#define CHUNKS 64
#define CHUNK_CODES 128
#define BMR 128              // x-rows per block
#define KC 32
#define KTILES (DIM / KC)    // 16

typedef short bf16x8 __attribute__((ext_vector_type(8)));
typedef float f32x4  __attribute__((ext_vector_type(4)));

// sorted ascending 2-slot insert (verified r5-r18)
__device__ __forceinline__ void t2_insert(u64* a, u64 k) {
    u64 lo = a[0], hi = a[1];
    bool lt0 = k < lo;
    u64 n1k = (k < hi) ? k : hi;
    a[0] = lt0 ? k : lo;
    a[1] = lt0 ? lo : n1k;
}

// ---------------- Kernel P: precompute bf16 HI-plane split only (verified r14-r18) ----
__global__ void vq_split_kernel(const float* __restrict__ x, const float* __restrict__ cb,
                                u16* __restrict__ xhi, u16* __restrict__ cbhi) {
    size_t t = (size_t)blockIdx.x * blockDim.x + threadIdx.x;
    const size_t nx = (size_t)N_ROWS * DIM / 4;
    const size_t nc = (size_t)K_CODES * DIM / 4;
    const float4* src;
    u16* hi;
    size_t off;
    if (t < nx)            { src = (const float4*)x;  hi = xhi;  off = t; }
    else if (t < nx + nc)  { src = (const float4*)cb; hi = cbhi; off = t - nx; }
    else return;
    float4 v = src[off];
    u16 h0 = (u16)(__float_as_uint(v.x) >> 16);
    u16 h1 = (u16)(__float_as_uint(v.y) >> 16);
    u16 h2 = (u16)(__float_as_uint(v.z) >> 16);
    u16 h3 = (u16)(__float_as_uint(v.w) >> 16);
    ((ushort4*)hi)[off] = make_ushort4(h0, h1, h2, h3);
}

// ---------------- Kernel N: numpy-pairwise fp32 row norms, wave-parallel (verified r18) ----
__global__ void vq_np_norm_kernel(const float* __restrict__ x, const float* __restrict__ cb,
                                  float* __restrict__ Arow, float* __restrict__ Bcode) {
    int wid = (blockIdx.x * blockDim.x + threadIdx.x) >> 6;
    int lane = threadIdx.x & 63;
    int r2 = lane >> 5;
    int b  = (lane >> 3) & 3;
    int j  = lane & 7;
    int row = wid * 2 + r2;
    const float* p;
    float* o;
    if (row < N_ROWS) { p = x + (size_t)row * DIM; o = Arow + row; }
    else              { int c = row - N_ROWS; p = cb + (size_t)c * DIM; o = Bcode + c; }
    const float* q = p + b * 128 + j;
    float v0 = q[0];
    float s = __fmul_rn(v0, v0);
    #pragma unroll
    for (int i = 1; i < 16; ++i) {
        float v = q[8 * i];
        s = __fadd_rn(s, __fmul_rn(v, v));
    }
    s = __fadd_rn(s, __shfl_xor(s, 1));
    s = __fadd_rn(s, __shfl_xor(s, 2));
    s = __fadd_rn(s, __shfl_xor(s, 4));
    s = __fadd_rn(s, __shfl_xor(s, 8));
    s = __fadd_rn(s, __shfl_xor(s, 16));
    if ((lane & 31) == 0) *o = s;
}

// ---------------- Kernel S: hh-only MFMA screen, r17 geometry + depth-2 prefetch ------
// Block = 128 rows x 128 codes, 4 waves 2x2, wave tile 64x64 (acc[4][4] = 64 AGPR;
// total regs ~136 <= 170 -> TRUE 3 blocks/CU). NBUF=3 x 16KB = 48KB/block.
// Depth-2: stage(kt+2) issued each iter; entry vmcnt(8) drains exactly stage kt,
// giving loads ~2 kt-periods to land. Numerics identical to r17/r18 (raw-dot
// screen, same MFMA order, same chunk geometry).
__launch_bounds__(256, 3)
__global__ void vq_screen_kernel(const u16* __restrict__ xhi, const u16* __restrict__ cbhi,
                                 u64* __restrict__ top2out) {
    __shared__ __align__(16) u16 lds[3][8192];   // 3 x 16KB: X[128][32] @0 | C[128][32] @4096

    const int t = threadIdx.x;
    const int lane = t & 63;
    const int w = t >> 6;        // 0..3
    const int wrow  = w >> 1;    // 0..1 -> x-rows [64*wrow, +64)
    const int wcode = w & 1;     // 0..1 -> codes  [64*wcode, +64)
    const int r15 = lane & 15;
    const int g = lane >> 4;     // 0..3
    const int cswz = (r15 >> 1) & 3;

    const int rowBase   = blockIdx.x * BMR;
    const int chunkBase = blockIdx.y * CHUNK_CODES;

    const size_t laneOff = (size_t)(lane >> 2) * DIM
                         + (size_t)(((lane & 3) ^ ((lane >> 3) & 3)) * 8);

    // 4 staging segments per wave: q = j*4 + w over [X groups 0-7 | C groups 8-15]
    const u16* srcs[4];
    int dsts[4];
    #pragma unroll
    for (int j = 0; j < 4; ++j) {
        int q = j * 4 + w;
        const u16* gp = (q < 8) ? (xhi + (size_t)(rowBase + q * 16) * DIM)
                                : (cbhi + (size_t)(chunkBase + (q - 8) * 16) * DIM);
        srcs[j] = gp + laneOff;
        dsts[j] = q * 512;
    }

    auto stage = [&](int kt) {
        u16* B = &lds[kt % 3][0];
        #pragma unroll
        for (int j = 0; j < 4; ++j) {
            __builtin_amdgcn_global_load_lds(
                (const __attribute__((address_space(1))) u32*)(srcs[j] + kt * KC),
                (__attribute__((address_space(3))) u32*)(B + dsts[j]),
                16, 0, 0);
        }
    };

    f32x4 acc[4][4] = {};   // [mi = code frag][ni = x-row frag]

    stage(0);
    stage(1);

    #pragma unroll
    for (int kt = 0; kt < KTILES; ++kt) {
        if (kt + 2 < KTILES) {
            stage(kt + 2);
            asm volatile("s_waitcnt vmcnt(8)" ::: "memory");
        } else if (kt + 1 < KTILES) {
            asm volatile("s_waitcnt vmcnt(4)" ::: "memory");
        } else {
            asm volatile("s_waitcnt vmcnt(0)" ::: "memory");
        }
        asm volatile("s_barrier" ::: "memory");

        const u16* L = &lds[kt % 3][0];
        bf16x8 Cf[4], Xf[4];
        #pragma unroll
        for (int mi = 0; mi < 4; ++mi)
            Cf[mi] = *(const bf16x8*)&L[4096 + (wcode * 64 + mi * 16 + r15) * 32 + (g ^ cswz) * 8];
        #pragma unroll
        for (int ni = 0; ni < 4; ++ni)
            Xf[ni] = *(const bf16x8*)&L[(wrow * 64 + ni * 16 + r15) * 32 + (g ^ cswz) * 8];
        __builtin_amdgcn_s_setprio(1);
        #pragma unroll
        for (int ni = 0; ni < 4; ++ni)
            #pragma unroll
            for (int mi = 0; mi < 4; ++mi)
                acc[mi][ni] = __builtin_amdgcn_mfma_f32_16x16x32_bf16(Cf[mi], Xf[ni], acc[mi][ni], 0, 0, 0);
        __builtin_amdgcn_s_setprio(0);
        asm volatile("s_barrier" ::: "memory");
    }

    // ---- fold: per x-row, top-2 MAX of raw dot over this lane's 16 codes ----
    __syncthreads();
    u64* t2buf = (u64*)&lds[0][0];   // [128 rows][2 wcode][2 slots] = 4KB

    #pragma unroll
    for (int ni = 0; ni < 4; ++ni) {
        const int xrow = wrow * 64 + ni * 16 + r15;
        float v0 = -3.4e38f, v1 = -3.4e38f;
        int   i0 = 0, i1 = 0;
        #pragma unroll
        for (int mi = 0; mi < 4; ++mi) {
            const int colBase = chunkBase + wcode * 64 + mi * 16 + g * 4;
            #pragma unroll
            for (int reg = 0; reg < 4; ++reg) {
                float v = acc[mi][ni][reg];
                int idx = colBase + reg;
                bool c0 = v > v0;
                bool c1 = v > v1;
                v1 = c0 ? v0 : (c1 ? v : v1);
                i1 = c0 ? i0 : (c1 ? idx : i1);
                v0 = c0 ? v : v0;
                i0 = c0 ? idx : i0;
            }
        }
        // merge across the 4 g-lanes (xor 16, 32); 16 rows merged in parallel
        #pragma unroll
        for (int m = 16; m <= 32; m <<= 1) {
            float ov0 = __shfl_xor(v0, m), ov1 = __shfl_xor(v1, m);
            int   oi0 = __shfl_xor(i0, m), oi1 = __shfl_xor(i1, m);
            bool aw = (v0 > ov0) || (v0 == ov0 && i0 < oi0);
            float wt = aw ? v0 : ov0;   int wi = aw ? i0 : oi0;
            float lt2 = aw ? ov0 : v0;  int li = aw ? oi0 : i0;
            float ws2 = aw ? v1 : ov1;  int si = aw ? i1 : oi1;
            bool sw = (lt2 > ws2) || (lt2 == ws2 && li < si);
            v0 = wt; i0 = wi;
            v1 = sw ? lt2 : ws2; i1 = sw ? li : si;
        }
        if (g == 0) {
            u32 s0 = __float_as_uint(v0);
            u32 km0 = (v0 < 0.0f) ? s0 : (~s0 & 0x7FFFFFFFu);
            u32 s1 = __float_as_uint(v1);
            u32 km1 = (v1 < 0.0f) ? s1 : (~s1 & 0x7FFFFFFFu);
            t2buf[(xrow * 2 + wcode) * 2 + 0] = ((u64)km0 << 13) | (u32)i0;
            t2buf[(xrow * 2 + wcode) * 2 + 1] = ((u64)km1 << 13) | (u32)i1;
        }
    }
    __syncthreads();
    if (t < BMR) {
        u64 best[2];
        best[0] = t2buf[(t * 2 + 0) * 2 + 0];
        best[1] = t2buf[(t * 2 + 0) * 2 + 1];
        t2_insert(best, t2buf[(t * 2 + 1) * 2 + 0]);
        t2_insert(best, t2buf[(t * 2 + 1) * 2 + 1]);
        size_t o = ((size_t)blockIdx.y * N_ROWS + rowBase + t) * 2;
        top2out[o + 0] = best[0];
        top2out[o + 1] = best[1];
    }
}

// ---------------- Kernel R: global top-8 of 64x2 keys -> exact np re-decision --------
__global__ void vq_refine_kernel(const float* __restrict__ x, const float* __restrict__ cb,
                                 const float* __restrict__ Arow, const float* __restrict__ Bcode,
                                 const u64* __restrict__ top2, int* __restrict__ idxOut,
                                 float* __restrict__ out4) {
    int gw = (blockIdx.x * blockDim.x + threadIdx.x) >> 6;
    int lane = threadIdx.x & 63;
    if (gw >= N_ROWS) return;

    const u64* tp = top2 + ((size_t)lane * N_ROWS + gw) * 2;
    u64 a0 = tp[0], a1 = tp[1];

    u64 cand[8];
    #pragma unroll
    for (int j = 0; j < 8; ++j) {
        u64 m = a0;
        #pragma unroll
        for (int s = 1; s < 64; s <<= 1) { u64 o = __shfl_xor(m, s); m = o < m ? o : m; }
        cand[j] = m;
        if (a0 == m) { a0 = a1; a1 = ~0ull; }
    }

    float Ai = Arow[gw];
    const float* xr = x + (size_t)gw * DIM;
    float xv[8];
    #pragma unroll
    for (int e = 0; e < 8; ++e) xv[e] = xr[e * 64 + lane];

    u64 best = ~0ull;
    #pragma unroll
    for (int j = 0; j < 8; ++j) {
        int c = (int)(cand[j] & 8191u);
        const float* er = cb + (size_t)c * DIM;
        double d = 0.0;
        #pragma unroll
        for (int e = 0; e < 8; ++e)
            d = fma((double)xv[e], (double)er[e * 64 + lane], d);
        #pragma unroll
        for (int m = 1; m < 64; m <<= 1) d += __shfl_xor(d, m);
        float m32 = (float)d;
        float dist = __fsub_rn(__fadd_rn(Ai, Bcode[c]), 2.0f * m32);
        u64 ek = ((u64)__float_as_uint(dist) << 13) | (u64)(u32)c;
        best = ek < best ? ek : best;
    }
    if (lane == 0) {
        int c = (int)(best & 8191u);
        idxOut[gw] = c;
        out4[gw] = (float)c;
    }
}

// ---------------- Kernel C: gather + outputs + per-row loss partial ----------------
__global__ void vq_gather_kernel(const float* __restrict__ x,
                                 const float* __restrict__ cb,
                                 const int* __restrict__ idxArr,
                                 float* __restrict__ out0,
                                 float* __restrict__ out3,
                                 float* __restrict__ rowPart) {
    int gw = (blockIdx.x * blockDim.x + threadIdx.x) >> 6;
    int lane = threadIdx.x & 63;
    if (gw >= N_ROWS) return;
    int idx = idxArr[gw];
    const float2* xp = (const float2*)(x  + (size_t)gw * DIM);
    const float2* qp = (const float2*)(cb + (size_t)idx * DIM);
    float2* o0 = (float2*)(out0 + (size_t)gw * DIM);
    float2* o3 = (float2*)(out3 + (size_t)gw * DIM);
    float part = 0.0f;
    #pragma unroll
    for (int r = 0; r < 4; ++r) {
        int e = r * 64 + lane;
        float2 xv = xp[e];
        float2 qv = qp[e];
        float dx = qv.x - xv.x, dy = qv.y - xv.y;
        part += dx * dx + dy * dy;
        float2 o; o.x = xv.x + dx; o.y = xv.y + dy;
        o0[e] = o;
        o3[e] = qv;
    }
    #pragma unroll
    for (int m = 32; m; m >>= 1) part += __shfl_xor(part, m);
    if (lane == 0) rowPart[gw] = part;
}

// ---------------- Kernel D: deterministic loss reduce ----------------
__global__ void vq_loss_kernel(const float* __restrict__ rowPart,
                               float* __restrict__ out1, float* __restrict__ out2) {
    __shared__ float red[256];
    int t = threadIdx.x;
    float s = 0.0f;
    for (int r = t; r < N_ROWS; r += 256) s += rowPart[r];
    red[t] = s;
    __syncthreads();
    #pragma unroll
    for (int m = 128; m; m >>= 1) {
        if (t < m) red[t] += red[t + m];
        __syncthreads();
    }
    if (t == 0) {
        float loss = red[0] / (float)(N_ROWS * DIM);
        out1[0] = loss;
        out2[0] = loss;
    }
}

extern "C" void kernel_launch(void* const* d_in, const int* in_sizes, int n_in,
                              void* d_out, int out_size, void* d_ws, size_t ws_size,
                              hipStream_t stream) {
    const float* x  = (const float*)d_in[0];   // [16384, 512]
    const float* cb = (const float*)d_in[1];   // [8192, 512]
    float* out  = (float*)d_out;
    float* out0 = out;                         // quantized_out [8388608]
    float* out1 = out + 8388608;               // q_latent_loss [1]
    float* out2 = out + 8388609;               // e_latent_loss [1]
    float* out3 = out + 8388610;               // quantized [8388608]
    float* out4 = out + 16777218;              // idx as float [16384]

    // d_out scratch (stream-ordered; consumed before gather overwrites):
    // xhi 16.8MB + cbhi 8.4MB in out0 region; top2 (64*16384*2 u64 = 16.8MB) in out3 region.
    u16* xhi    = (u16*)out0;                  // [0, 4194304) floats
    u16* cbhi   = (u16*)(out + 4194304);       // [4194304, 6291456)
    u64* wsTop2 = (u64*)(out + 8388612);       // [8388612, 12582916)  8B-aligned

    char* ws = (char*)d_ws;
    float* wsA    = (float*)ws;                // 16384 f
    float* wsB    = (float*)(ws + 65536);      // 8192 f
    int*   wsIdx  = (int*)(ws + 98304);        // 16384 int
    float* wsPart = (float*)(ws + 163840);     // 16384 f

    hipLaunchKernelGGL(vq_split_kernel,   dim3(12288), dim3(256), 0, stream,
                       x, cb, xhi, cbhi);
    hipLaunchKernelGGL(vq_np_norm_kernel, dim3(3072), dim3(256), 0, stream, x, cb, wsA, wsB);
    hipLaunchKernelGGL(vq_screen_kernel,  dim3(N_ROWS / BMR, CHUNKS), dim3(256), 0, stream,
                       xhi, cbhi, wsTop2);
    hipLaunchKernelGGL(vq_refine_kernel,  dim3(4096), dim3(256), 0, stream,
                       x, cb, wsA, wsB, wsTop2, wsIdx, out4);
    hipLaunchKernelGGL(vq_gather_kernel,  dim3(4096), dim3(256), 0, stream,
                       x, cb, wsIdx, out0, out3, wsPart);
    hipLaunchKernelGGL(vq_loss_kernel,    dim3(1),    dim3(256), 0, stream,
                       wsPart, out1, out2);
}

// Round 21
// 259.899 us; speedup vs baseline: 2.3971x; 1.0051x over previous
//
#include <hip/hip_runtime.h>

typedef unsigned long long u64;
typedef unsigned int u32;
typedef unsigned short u16;

#define N_ROWS 16384
#define DIM    512
#define K_CODES 8192

#define CHUNKS 64
#define CHUNK_CODES 128
#define BMR 128              // x-rows per block
#define KC 32
#define KTILES (DIM / KC)    // 16

typedef short bf16x8 __attribute__((ext_vector_type(8)));
typedef float f32x4  __attribute__((ext_vector_type(4)));

// sorted ascending 2-slot insert (verified r5-r20)
__device__ __forceinline__ void t2_insert(u64* a, u64 k) {
    u64 lo = a[0], hi = a[1];
    bool lt0 = k < lo;
    u64 n1k = (k < hi) ? k : hi;
    a[0] = lt0 ? k : lo;
    a[1] = lt0 ? lo : n1k;
}

// ---------------- Kernel P: precompute bf16 HI-plane split only (verified r14-r20) ----
__global__ void vq_split_kernel(const float* __restrict__ x, const float* __restrict__ cb,
                                u16* __restrict__ xhi, u16* __restrict__ cbhi) {
    size_t t = (size_t)blockIdx.x * blockDim.x + threadIdx.x;
    const size_t nx = (size_t)N_ROWS * DIM / 4;
    const size_t nc = (size_t)K_CODES * DIM / 4;
    const float4* src;
    u16* hi;
    size_t off;
    if (t < nx)            { src = (const float4*)x;  hi = xhi;  off = t; }
    else if (t < nx + nc)  { src = (const float4*)cb; hi = cbhi; off = t - nx; }
    else return;
    float4 v = src[off];
    u16 h0 = (u16)(__float_as_uint(v.x) >> 16);
    u16 h1 = (u16)(__float_as_uint(v.y) >> 16);
    u16 h2 = (u16)(__float_as_uint(v.z) >> 16);
    u16 h3 = (u16)(__float_as_uint(v.w) >> 16);
    ((ushort4*)hi)[off] = make_ushort4(h0, h1, h2, h3);
}

// ---------------- Kernel N: numpy-pairwise fp32 row norms, wave-parallel (verified r18) ----
__global__ void vq_np_norm_kernel(const float* __restrict__ x, const float* __restrict__ cb,
                                  float* __restrict__ Arow, float* __restrict__ Bcode) {
    int wid = (blockIdx.x * blockDim.x + threadIdx.x) >> 6;
    int lane = threadIdx.x & 63;
    int r2 = lane >> 5;
    int b  = (lane >> 3) & 3;
    int j  = lane & 7;
    int row = wid * 2 + r2;
    const float* p;
    float* o;
    if (row < N_ROWS) { p = x + (size_t)row * DIM; o = Arow + row; }
    else              { int c = row - N_ROWS; p = cb + (size_t)c * DIM; o = Bcode + c; }
    const float* q = p + b * 128 + j;
    float v0 = q[0];
    float s = __fmul_rn(v0, v0);
    #pragma unroll
    for (int i = 1; i < 16; ++i) {
        float v = q[8 * i];
        s = __fadd_rn(s, __fmul_rn(v, v));
    }
    s = __fadd_rn(s, __shfl_xor(s, 1));
    s = __fadd_rn(s, __shfl_xor(s, 2));
    s = __fadd_rn(s, __shfl_xor(s, 4));
    s = __fadd_rn(s, __shfl_xor(s, 8));
    s = __fadd_rn(s, __shfl_xor(s, 16));
    if ((lane & 31) == 0) *o = s;
}

// ---------------- Kernel S: hh-only screen, reads-ahead pipeline, 3 blocks/CU --------
// r20 geometry (128x128 block, 4 waves, 64x64 wave tile, NBUF=3) with register
// double-buffered fragments: frags(kt+1) are ds_read UNDER MFMA(kt) (no intra-
// iteration lgkm dependency -> LDS and MFMA pipes run concurrently per wave).
// vmcnt(4) at iter kt drains exactly stage(kt+1); WAR on buffers is 2-barrier
// separated. MFMA order/fragments identical to r17-r20 -> bit-identical outputs.
__launch_bounds__(256, 3)
__global__ void vq_screen_kernel(const u16* __restrict__ xhi, const u16* __restrict__ cbhi,
                                 u64* __restrict__ top2out) {
    __shared__ __align__(16) u16 lds[3][8192];   // 3 x 16KB: X[128][32] @0 | C[128][32] @4096

    const int t = threadIdx.x;
    const int lane = t & 63;
    const int w = t >> 6;        // 0..3
    const int wrow  = w >> 1;    // 0..1 -> x-rows [64*wrow, +64)
    const int wcode = w & 1;     // 0..1 -> codes  [64*wcode, +64)
    const int r15 = lane & 15;
    const int g = lane >> 4;     // 0..3
    const int cswz = (r15 >> 1) & 3;

    const int rowBase   = blockIdx.x * BMR;
    const int chunkBase = blockIdx.y * CHUNK_CODES;

    const size_t laneOff = (size_t)(lane >> 2) * DIM
                         + (size_t)(((lane & 3) ^ ((lane >> 3) & 3)) * 8);

    const u16* srcs[4];
    int dsts[4];
    #pragma unroll
    for (int j = 0; j < 4; ++j) {
        int q = j * 4 + w;
        const u16* gp = (q < 8) ? (xhi + (size_t)(rowBase + q * 16) * DIM)
                                : (cbhi + (size_t)(chunkBase + (q - 8) * 16) * DIM);
        srcs[j] = gp + laneOff;
        dsts[j] = q * 512;
    }

    auto stage = [&](int kt) {
        u16* B = &lds[kt % 3][0];
        #pragma unroll
        for (int j = 0; j < 4; ++j) {
            __builtin_amdgcn_global_load_lds(
                (const __attribute__((address_space(1))) u32*)(srcs[j] + kt * KC),
                (__attribute__((address_space(3))) u32*)(B + dsts[j]),
                16, 0, 0);
        }
    };

    const int aOff = (wrow * 64 + r15) * 32;          // + mi*512
    const int cOff = 4096 + (wcode * 64 + r15) * 32;  // + mi*512
    const int kSel = (g ^ cswz) * 8;

    auto readFrags = [&](int kt, bf16x8 (&Cf)[4], bf16x8 (&Xf)[4]) {
        const u16* L = &lds[kt % 3][0];
        #pragma unroll
        for (int mi = 0; mi < 4; ++mi)
            Cf[mi] = *(const bf16x8*)&L[cOff + mi * 512 + kSel];
        #pragma unroll
        for (int ni = 0; ni < 4; ++ni)
            Xf[ni] = *(const bf16x8*)&L[aOff + ni * 512 + kSel];
    };

    f32x4 acc[4][4] = {};   // [mi = code frag][ni = x-row frag]

    auto mfmaStep = [&](bf16x8 (&Cf)[4], bf16x8 (&Xf)[4]) {
        __builtin_amdgcn_s_setprio(1);
        #pragma unroll
        for (int ni = 0; ni < 4; ++ni)
            #pragma unroll
            for (int mi = 0; mi < 4; ++mi)
                acc[mi][ni] = __builtin_amdgcn_mfma_f32_16x16x32_bf16(Cf[mi], Xf[ni], acc[mi][ni], 0, 0, 0);
        __builtin_amdgcn_s_setprio(0);
    };

    bf16x8 CfA[4], XfA[4], CfB[4], XfB[4];

    stage(0);
    stage(1);
    asm volatile("s_waitcnt vmcnt(4)" ::: "memory");   // stage(0) complete
    asm volatile("s_barrier" ::: "memory");
    readFrags(0, CfA, XfA);

    #pragma unroll
    for (int kt2 = 0; kt2 < KTILES / 2; ++kt2) {
        const int kt = 2 * kt2;
        // ---- even iter kt: MFMA(A=kt), read B=frags(kt+1) under it ----
        if (kt + 2 < KTILES) {
            stage(kt + 2);
            asm volatile("s_waitcnt vmcnt(4)" ::: "memory");   // stage(kt+1) complete
        } else {
            asm volatile("s_waitcnt vmcnt(0)" ::: "memory");   // stage(15) complete
        }
        asm volatile("s_barrier" ::: "memory");
        readFrags(kt + 1, CfB, XfB);
        mfmaStep(CfA, XfA);

        // ---- odd iter kt+1: MFMA(B=kt+1), read A=frags(kt+2) under it ----
        if (kt + 2 < KTILES) {
            if (kt + 3 < KTILES) {
                stage(kt + 3);
                asm volatile("s_waitcnt vmcnt(4)" ::: "memory");   // stage(kt+2) complete
            } else {
                asm volatile("s_waitcnt vmcnt(0)" ::: "memory");
            }
            asm volatile("s_barrier" ::: "memory");
            readFrags(kt + 2, CfA, XfA);
        }
        mfmaStep(CfB, XfB);
    }

    // ---- fold: per x-row, top-2 MAX of raw dot over this lane's 16 codes ----
    __syncthreads();
    u64* t2buf = (u64*)&lds[0][0];   // [128 rows][2 wcode][2 slots] = 4KB

    #pragma unroll
    for (int ni = 0; ni < 4; ++ni) {
        const int xrow = wrow * 64 + ni * 16 + r15;
        float v0 = -3.4e38f, v1 = -3.4e38f;
        int   i0 = 0, i1 = 0;
        #pragma unroll
        for (int mi = 0; mi < 4; ++mi) {
            const int colBase = chunkBase + wcode * 64 + mi * 16 + g * 4;
            #pragma unroll
            for (int reg = 0; reg < 4; ++reg) {
                float v = acc[mi][ni][reg];
                int idx = colBase + reg;
                bool c0 = v > v0;
                bool c1 = v > v1;
                v1 = c0 ? v0 : (c1 ? v : v1);
                i1 = c0 ? i0 : (c1 ? idx : i1);
                v0 = c0 ? v : v0;
                i0 = c0 ? idx : i0;
            }
        }
        // merge across the 4 g-lanes (xor 16, 32); 16 rows merged in parallel
        #pragma unroll
        for (int m = 16; m <= 32; m <<= 1) {
            float ov0 = __shfl_xor(v0, m), ov1 = __shfl_xor(v1, m);
            int   oi0 = __shfl_xor(i0, m), oi1 = __shfl_xor(i1, m);
            bool aw = (v0 > ov0) || (v0 == ov0 && i0 < oi0);
            float wt = aw ? v0 : ov0;   int wi = aw ? i0 : oi0;
            float lt2 = aw ? ov0 : v0;  int li = aw ? oi0 : i0;
            float ws2 = aw ? v1 : ov1;  int si = aw ? i1 : oi1;
            bool sw = (lt2 > ws2) || (lt2 == ws2 && li < si);
            v0 = wt; i0 = wi;
            v1 = sw ? lt2 : ws2; i1 = sw ? li : si;
        }
        if (g == 0) {
            u32 s0 = __float_as_uint(v0);
            u32 km0 = (v0 < 0.0f) ? s0 : (~s0 & 0x7FFFFFFFu);
            u32 s1 = __float_as_uint(v1);
            u32 km1 = (v1 < 0.0f) ? s1 : (~s1 & 0x7FFFFFFFu);
            t2buf[(xrow * 2 + wcode) * 2 + 0] = ((u64)km0 << 13) | (u32)i0;
            t2buf[(xrow * 2 + wcode) * 2 + 1] = ((u64)km1 << 13) | (u32)i1;
        }
    }
    __syncthreads();
    if (t < BMR) {
        u64 best[2];
        best[0] = t2buf[(t * 2 + 0) * 2 + 0];
        best[1] = t2buf[(t * 2 + 0) * 2 + 1];
        t2_insert(best, t2buf[(t * 2 + 1) * 2 + 0]);
        t2_insert(best, t2buf[(t * 2 + 1) * 2 + 1]);
        size_t o = ((size_t)blockIdx.y * N_ROWS + rowBase + t) * 2;
        top2out[o + 0] = best[0];
        top2out[o + 1] = best[1];
    }
}

// ---------------- Kernel R: global top-8 of 64x2 keys -> exact np re-decision --------
__global__ void vq_refine_kernel(const float* __restrict__ x, const float* __restrict__ cb,
                                 const float* __restrict__ Arow, const float* __restrict__ Bcode,
                                 const u64* __restrict__ top2, int* __restrict__ idxOut,
                                 float* __restrict__ out4) {
    int gw = (blockIdx.x * blockDim.x + threadIdx.x) >> 6;
    int lane = threadIdx.x & 63;
    if (gw >= N_ROWS) return;

    const u64* tp = top2 + ((size_t)lane * N_ROWS + gw) * 2;
    u64 a0 = tp[0], a1 = tp[1];

    u64 cand[8];
    #pragma unroll
    for (int j = 0; j < 8; ++j) {
        u64 m = a0;
        #pragma unroll
        for (int s = 1; s < 64; s <<= 1) { u64 o = __shfl_xor(m, s); m = o < m ? o : m; }
        cand[j] = m;
        if (a0 == m) { a0 = a1; a1 = ~0ull; }
    }

    float Ai = Arow[gw];
    const float* xr = x + (size_t)gw * DIM;
    float xv[8];
    #pragma unroll
    for (int e = 0; e < 8; ++e) xv[e] = xr[e * 64 + lane];

    u64 best = ~0ull;
    #pragma unroll
    for (int j = 0; j < 8; ++j) {
        int c = (int)(cand[j] & 8191u);
        const float* er = cb + (size_t)c * DIM;
        double d = 0.0;
        #pragma unroll
        for (int e = 0; e < 8; ++e)
            d = fma((double)xv[e], (double)er[e * 64 + lane], d);
        #pragma unroll
        for (int m = 1; m < 64; m <<= 1) d += __shfl_xor(d, m);
        float m32 = (float)d;
        float dist = __fsub_rn(__fadd_rn(Ai, Bcode[c]), 2.0f * m32);
        u64 ek = ((u64)__float_as_uint(dist) << 13) | (u64)(u32)c;
        best = ek < best ? ek : best;
    }
    if (lane == 0) {
        int c = (int)(best & 8191u);
        idxOut[gw] = c;
        out4[gw] = (float)c;
    }
}

// ---------------- Kernel C: gather + outputs + per-row loss partial ----------------
__global__ void vq_gather_kernel(const float* __restrict__ x,
                                 const float* __restrict__ cb,
                                 const int* __restrict__ idxArr,
                                 float* __restrict__ out0,
                                 float* __restrict__ out3,
                                 float* __restrict__ rowPart) {
    int gw = (blockIdx.x * blockDim.x + threadIdx.x) >> 6;
    int lane = threadIdx.x & 63;
    if (gw >= N_ROWS) return;
    int idx = idxArr[gw];
    const float2* xp = (const float2*)(x  + (size_t)gw * DIM);
    const float2* qp = (const float2*)(cb + (size_t)idx * DIM);
    float2* o0 = (float2*)(out0 + (size_t)gw * DIM);
    float2* o3 = (float2*)(out3 + (size_t)gw * DIM);
    float part = 0.0f;
    #pragma unroll
    for (int r = 0; r < 4; ++r) {
        int e = r * 64 + lane;
        float2 xv = xp[e];
        float2 qv = qp[e];
        float dx = qv.x - xv.x, dy = qv.y - xv.y;
        part += dx * dx + dy * dy;
        float2 o; o.x = xv.x + dx; o.y = xv.y + dy;
        o0[e] = o;
        o3[e] = qv;
    }
    #pragma unroll
    for (int m = 32; m; m >>= 1) part += __shfl_xor(part, m);
    if (lane == 0) rowPart[gw] = part;
}

// ---------------- Kernel D: deterministic loss reduce ----------------
__global__ void vq_loss_kernel(const float* __restrict__ rowPart,
                               float* __restrict__ out1, float* __restrict__ out2) {
    __shared__ float red[256];
    int t = threadIdx.x;
    float s = 0.0f;
    for (int r = t; r < N_ROWS; r += 256) s += rowPart[r];
    red[t] = s;
    __syncthreads();
    #pragma unroll
    for (int m = 128; m; m >>= 1) {
        if (t < m) red[t] += red[t + m];
        __syncthreads();
    }
    if (t == 0) {
        float loss = red[0] / (float)(N_ROWS * DIM);
        out1[0] = loss;
        out2[0] = loss;
    }
}

extern "C" void kernel_launch(void* const* d_in, const int* in_sizes, int n_in,
                              void* d_out, int out_size, void* d_ws, size_t ws_size,
                              hipStream_t stream) {
    const float* x  = (const float*)d_in[0];   // [16384, 512]
    const float* cb = (const float*)d_in[1];   // [8192, 512]
    float* out  = (float*)d_out;
    float* out0 = out;                         // quantized_out [8388608]
    float* out1 = out + 8388608;               // q_latent_loss [1]
    float* out2 = out + 8388609;               // e_latent_loss [1]
    float* out3 = out + 8388610;               // quantized [8388608]
    float* out4 = out + 16777218;              // idx as float [16384]

    // d_out scratch (stream-ordered; consumed before gather overwrites):
    // xhi 16.8MB + cbhi 8.4MB in out0 region; top2 (64*16384*2 u64 = 16.8MB) in out3 region.
    u16* xhi    = (u16*)out0;                  // [0, 4194304) floats
    u16* cbhi   = (u16*)(out + 4194304);       // [4194304, 6291456)
    u64* wsTop2 = (u64*)(out + 8388612);       // [8388612, 12582916)  8B-aligned

    char* ws = (char*)d_ws;
    float* wsA    = (float*)ws;                // 16384 f
    float* wsB    = (float*)(ws + 65536);      // 8192 f
    int*   wsIdx  = (int*)(ws + 98304);        // 16384 int
    float* wsPart = (float*)(ws + 163840);     // 16384 f

    hipLaunchKernelGGL(vq_split_kernel,   dim3(12288), dim3(256), 0, stream,
                       x, cb, xhi, cbhi);
    hipLaunchKernelGGL(vq_np_norm_kernel, dim3(3072), dim3(256), 0, stream, x, cb, wsA, wsB);
    hipLaunchKernelGGL(vq_screen_kernel,  dim3(N_ROWS / BMR, CHUNKS), dim3(256), 0, stream,
                       xhi, cbhi, wsTop2);
    hipLaunchKernelGGL(vq_refine_kernel,  dim3(4096), dim3(256), 0, stream,
                       x, cb, wsA, wsB, wsTop2, wsIdx, out4);
    hipLaunchKernelGGL(vq_gather_kernel,  dim3(4096), dim3(256), 0, stream,
                       x, cb, wsIdx, out0, out3, wsPart);
    hipLaunchKernelGGL(vq_loss_kernel,    dim3(1),    dim3(256), 0, stream,
                       wsPart, out1, out2);
}

// Round 22
// 204.186 us; speedup vs baseline: 3.0512x; 1.2729x over previous
//
#include <hip/hip_runtime.h>

typedef unsigned long long u64;
typedef unsigned int u32;
typedef unsigned short u16;
typedef unsigned char u8;

#define N_ROWS 16384
#define DIM    512
#define K_CODES 8192

#define CHUNKS 64
#define CHUNK_CODES 128
#define BMR 128
#define KC 64                 // fp8 k-elems per tile
#define KTILES (DIM / KC)     // 8

typedef int   i32x4  __attribute__((ext_vector_type(4)));
typedef int   i32x8  __attribute__((ext_vector_type(8)));
typedef float f32x16 __attribute__((ext_vector_type(16)));

// sorted ascending 3-slot insert (r14-verified)
__device__ __forceinline__ void t3_insert(u64* a, u64 k) {
    u64 x = k;
    bool l0 = x < a[0]; u64 n0 = l0 ? x : a[0]; x = l0 ? a[0] : x;
    bool l1 = x < a[1]; u64 n1 = l1 ? x : a[1]; x = l1 ? a[1] : x;
    bool l2 = x < a[2]; u64 n2 = l2 ? x : a[2];
    a[0] = n0; a[1] = n1; a[2] = n2;
}

// ---------------- Kernel P: fp8 e4m3 split; cb pre-scaled by 2^13 (rank-invariant) ----
__global__ void vq_split_kernel(const float* __restrict__ x, const float* __restrict__ cb,
                                u32* __restrict__ xf8, u32* __restrict__ cf8) {
    size_t t = (size_t)blockIdx.x * blockDim.x + threadIdx.x;
    const size_t nx = (size_t)N_ROWS * DIM / 4;
    const size_t nc = (size_t)K_CODES * DIM / 4;
    if (t < nx) {
        float4 v = ((const float4*)x)[t];
        u32 r = (u32)__builtin_amdgcn_cvt_pk_fp8_f32(v.x, v.y, 0, false);
        r = (u32)__builtin_amdgcn_cvt_pk_fp8_f32(v.z, v.w, (int)r, true);
        xf8[t] = r;
    } else if (t < nx + nc) {
        float4 v = ((const float4*)cb)[t - nx];
        u32 r = (u32)__builtin_amdgcn_cvt_pk_fp8_f32(v.x * 8192.0f, v.y * 8192.0f, 0, false);
        r = (u32)__builtin_amdgcn_cvt_pk_fp8_f32(v.z * 8192.0f, v.w * 8192.0f, (int)r, true);
        cf8[t - nx] = r;
    }
}

// ---------------- Kernel N: numpy-pairwise fp32 row norms, wave-parallel (verified r18) ----
__global__ void vq_np_norm_kernel(const float* __restrict__ x, const float* __restrict__ cb,
                                  float* __restrict__ Arow, float* __restrict__ Bcode) {
    int wid = (blockIdx.x * blockDim.x + threadIdx.x) >> 6;
    int lane = threadIdx.x & 63;
    int r2 = lane >> 5;
    int b  = (lane >> 3) & 3;
    int j  = lane & 7;
    int row = wid * 2 + r2;
    const float* p;
    float* o;
    if (row < N_ROWS) { p = x + (size_t)row * DIM; o = Arow + row; }
    else              { int c = row - N_ROWS; p = cb + (size_t)c * DIM; o = Bcode + c; }
    const float* q = p + b * 128 + j;
    float v0 = q[0];
    float s = __fmul_rn(v0, v0);
    #pragma unroll
    for (int i = 1; i < 16; ++i) {
        float v = q[8 * i];
        s = __fadd_rn(s, __fmul_rn(v, v));
    }
    s = __fadd_rn(s, __shfl_xor(s, 1));
    s = __fadd_rn(s, __shfl_xor(s, 2));
    s = __fadd_rn(s, __shfl_xor(s, 4));
    s = __fadd_rn(s, __shfl_xor(s, 8));
    s = __fadd_rn(s, __shfl_xor(s, 16));
    if ((lane & 31) == 0) *o = s;
}

// ---------------- Kernel S: fp8 MX-scaled (identity) MFMA screen ------------------
// 128 rows x 128 codes per block, 4 waves 2x2, wave tile 64x64 = 2x2 of 32x32x64.
// acc = 4 x f32x16 = 64 AGPR -> 3 blocks/CU. NBUF=3 x 16KB; r20 depth-2 vmcnt(8).
// Screen score = raw fp8 dot (scaled 2^13; rank-invariant). Top-3/chunk (fp8 noise
// ~5% of sigma_dot demands the extra slot) + global top-8 exact refine.
__launch_bounds__(256, 3)
__global__ void vq_screen_kernel(const u8* __restrict__ xf8, const u8* __restrict__ cf8,
                                 u64* __restrict__ top3out) {
    __shared__ __align__(16) u8 lds[3][16384];   // X[128][64] @0 | C[128][64] @8192

    const int t = threadIdx.x;
    const int lane = t & 63;
    const int w = t >> 6;        // 0..3
    const int wrow  = w >> 1;    // 0..1 -> x-rows [64*wrow, +64)
    const int wcode = w & 1;     // 0..1 -> codes  [64*wcode, +64)
    const int l31 = lane & 31;
    const int h = lane >> 5;     // k-half selector

    const int rowBase   = blockIdx.x * BMR;
    const int chunkBase = blockIdx.y * CHUNK_CODES;

    // staging: 16 segs of 1KB (16 rows x 64B); pre-swizzled source chunk
    const size_t laneOff = (size_t)(lane >> 2) * DIM
                         + (size_t)(((lane & 3) ^ ((lane >> 3) & 3)) * 16);
    const u8* srcs[4];
    int dsts[4];
    #pragma unroll
    for (int j = 0; j < 4; ++j) {
        int q = j * 4 + w;
        const u8* gp = (q < 8) ? (xf8 + (size_t)(rowBase + q * 16) * DIM)
                               : (cf8 + (size_t)(chunkBase + (q - 8) * 16) * DIM);
        srcs[j] = gp + laneOff;
        dsts[j] = q * 1024;
    }

    auto stage = [&](int kt) {
        u8* B = &lds[kt % 3][0];
        #pragma unroll
        for (int j = 0; j < 4; ++j) {
            __builtin_amdgcn_global_load_lds(
                (const __attribute__((address_space(1))) u32*)(srcs[j] + kt * KC),
                (__attribute__((address_space(3))) u32*)(B + dsts[j]),
                16, 0, 0);
        }
    };

    // fragment LDS byte offsets (kt-invariant); slot = (h*2+b) ^ ((row>>1)&3)
    const int swz = (l31 >> 1) & 3;
    const int s0 = ((h * 2 + 0) ^ swz) * 16;
    const int s1 = ((h * 2 + 1) ^ swz) * 16;
    int aOff0[2], aOff1[2], bOff0[2], bOff1[2];
    #pragma unroll
    for (int mi = 0; mi < 2; ++mi) {
        int rc = wcode * 64 + mi * 32 + l31;
        aOff0[mi] = 8192 + rc * 64 + s0;
        aOff1[mi] = 8192 + rc * 64 + s1;
    }
    #pragma unroll
    for (int ni = 0; ni < 2; ++ni) {
        int rx = wrow * 64 + ni * 32 + l31;
        bOff0[ni] = rx * 64 + s0;
        bOff1[ni] = rx * 64 + s1;
    }

    f32x16 acc[2][2] = {};

    stage(0);
    stage(1);

    #pragma unroll
    for (int kt = 0; kt < KTILES; ++kt) {
        if (kt + 2 < KTILES) {
            stage(kt + 2);
            asm volatile("s_waitcnt vmcnt(8)" ::: "memory");
        } else if (kt + 1 < KTILES) {
            asm volatile("s_waitcnt vmcnt(4)" ::: "memory");
        } else {
            asm volatile("s_waitcnt vmcnt(0)" ::: "memory");
        }
        asm volatile("s_barrier" ::: "memory");

        const u8* L = &lds[kt % 3][0];
        i32x8 Af[2], Bf[2];
        #pragma unroll
        for (int mi = 0; mi < 2; ++mi) {
            i32x4 lo = *(const i32x4*)(L + aOff0[mi]);
            i32x4 hi = *(const i32x4*)(L + aOff1[mi]);
            Af[mi][0] = lo[0]; Af[mi][1] = lo[1]; Af[mi][2] = lo[2]; Af[mi][3] = lo[3];
            Af[mi][4] = hi[0]; Af[mi][5] = hi[1]; Af[mi][6] = hi[2]; Af[mi][7] = hi[3];
        }
        #pragma unroll
        for (int ni = 0; ni < 2; ++ni) {
            i32x4 lo = *(const i32x4*)(L + bOff0[ni]);
            i32x4 hi = *(const i32x4*)(L + bOff1[ni]);
            Bf[ni][0] = lo[0]; Bf[ni][1] = lo[1]; Bf[ni][2] = lo[2]; Bf[ni][3] = lo[3];
            Bf[ni][4] = hi[0]; Bf[ni][5] = hi[1]; Bf[ni][6] = hi[2]; Bf[ni][7] = hi[3];
        }
        __builtin_amdgcn_s_setprio(1);
        #pragma unroll
        for (int ni = 0; ni < 2; ++ni)
            #pragma unroll
            for (int mi = 0; mi < 2; ++mi)
                acc[mi][ni] = __builtin_amdgcn_mfma_scale_f32_32x32x64_f8f6f4(
                    Af[mi], Bf[ni], acc[mi][ni], 0, 0, 0, 127, 0, 127);
        __builtin_amdgcn_s_setprio(0);
        asm volatile("s_barrier" ::: "memory");
    }

    // ---- fold: 32x32 C layout (col=lane&31=xrow; code=(reg&3)+8*(reg>>2)+4*h) ----
    __syncthreads();
    u64* t3buf = (u64*)&lds[0][0];   // [128 rows][2 wcode][3 slots] = 6KB

    #pragma unroll
    for (int ni = 0; ni < 2; ++ni) {
        float v0 = -3.4e38f, v1 = -3.4e38f, v2 = -3.4e38f;
        int   i0 = 0, i1 = 0, i2 = 0;
        #pragma unroll
        for (int mi = 0; mi < 2; ++mi) {
            const int cb0 = chunkBase + wcode * 64 + mi * 32 + 4 * h;
            #pragma unroll
            for (int reg = 0; reg < 16; ++reg) {
                float v = acc[mi][ni][reg];
                int idx = cb0 + (reg & 3) + 8 * (reg >> 2);
                bool c0 = v > v0, c1 = v > v1, c2 = v > v2;
                v2 = c1 ? v1 : (c2 ? v : v2); i2 = c1 ? i1 : (c2 ? idx : i2);
                v1 = c0 ? v0 : (c1 ? v : v1); i1 = c0 ? i0 : (c1 ? idx : i1);
                v0 = c0 ? v  : v0;            i0 = c0 ? idx : i0;
            }
        }
        // merge with lane^32 (same xrow, complementary codes)
        float w0 = __shfl_xor(v0, 32), w1 = __shfl_xor(v1, 32), w2 = __shfl_xor(v2, 32);
        int   j0 = __shfl_xor(i0, 32), j1 = __shfl_xor(i1, 32), j2 = __shfl_xor(i2, 32);
        #pragma unroll
        for (int s = 0; s < 3; ++s) {
            float ov = (s == 0) ? w0 : (s == 1) ? w1 : w2;
            int   oi = (s == 0) ? j0 : (s == 1) ? j1 : j2;
            bool c0 = ov > v0, c1 = ov > v1, c2 = ov > v2;
            v2 = c1 ? v1 : (c2 ? ov : v2); i2 = c1 ? i1 : (c2 ? oi : i2);
            v1 = c0 ? v0 : (c1 ? ov : v1); i1 = c0 ? i0 : (c1 ? oi : i1);
            v0 = c0 ? ov : v0;             i0 = c0 ? oi  : i0;
        }
        if (h == 0) {
            int xrl = wrow * 64 + ni * 32 + l31;
            u32 b0 = __float_as_uint(v0);
            u32 k0 = (v0 < 0.0f) ? b0 : (~b0 & 0x7FFFFFFFu);
            u32 b1 = __float_as_uint(v1);
            u32 k1 = (v1 < 0.0f) ? b1 : (~b1 & 0x7FFFFFFFu);
            u32 b2 = __float_as_uint(v2);
            u32 k2 = (v2 < 0.0f) ? b2 : (~b2 & 0x7FFFFFFFu);
            t3buf[(xrl * 2 + wcode) * 3 + 0] = ((u64)k0 << 13) | (u32)i0;
            t3buf[(xrl * 2 + wcode) * 3 + 1] = ((u64)k1 << 13) | (u32)i1;
            t3buf[(xrl * 2 + wcode) * 3 + 2] = ((u64)k2 << 13) | (u32)i2;
        }
    }
    __syncthreads();
    if (t < BMR) {
        u64 best[3];
        best[0] = t3buf[(t * 2 + 0) * 3 + 0];
        best[1] = t3buf[(t * 2 + 0) * 3 + 1];
        best[2] = t3buf[(t * 2 + 0) * 3 + 2];
        t3_insert(best, t3buf[(t * 2 + 1) * 3 + 0]);
        t3_insert(best, t3buf[(t * 2 + 1) * 3 + 1]);
        t3_insert(best, t3buf[(t * 2 + 1) * 3 + 2]);
        size_t o = ((size_t)blockIdx.y * N_ROWS + rowBase + t) * 3;
        top3out[o + 0] = best[0];
        top3out[o + 1] = best[1];
        top3out[o + 2] = best[2];
    }
}

// ---------------- Kernel R: global top-8 of 64x3 keys -> exact np re-decision (r14) ---
__global__ void vq_refine_kernel(const float* __restrict__ x, const float* __restrict__ cb,
                                 const float* __restrict__ Arow, const float* __restrict__ Bcode,
                                 const u64* __restrict__ top3, int* __restrict__ idxOut,
                                 float* __restrict__ out4) {
    int gw = (blockIdx.x * blockDim.x + threadIdx.x) >> 6;
    int lane = threadIdx.x & 63;
    if (gw >= N_ROWS) return;

    const u64* tp = top3 + ((size_t)lane * N_ROWS + gw) * 3;
    u64 a0 = tp[0], a1 = tp[1], a2 = tp[2];

    u64 cand[8];
    #pragma unroll
    for (int j = 0; j < 8; ++j) {
        u64 m = a0;
        #pragma unroll
        for (int s = 1; s < 64; s <<= 1) { u64 o = __shfl_xor(m, s); m = o < m ? o : m; }
        cand[j] = m;
        if (a0 == m) { a0 = a1; a1 = a2; a2 = ~0ull; }
    }

    float Ai = Arow[gw];
    const float* xr = x + (size_t)gw * DIM;
    float xv[8];
    #pragma unroll
    for (int e = 0; e < 8; ++e) xv[e] = xr[e * 64 + lane];

    u64 best = ~0ull;
    #pragma unroll
    for (int j = 0; j < 8; ++j) {
        int c = (int)(cand[j] & 8191u);
        const float* er = cb + (size_t)c * DIM;
        double d = 0.0;
        #pragma unroll
        for (int e = 0; e < 8; ++e)
            d = fma((double)xv[e], (double)er[e * 64 + lane], d);
        #pragma unroll
        for (int m = 1; m < 64; m <<= 1) d += __shfl_xor(d, m);
        float m32 = (float)d;
        float dist = __fsub_rn(__fadd_rn(Ai, Bcode[c]), 2.0f * m32);
        u64 ek = ((u64)__float_as_uint(dist) << 13) | (u64)(u32)c;
        best = ek < best ? ek : best;
    }
    if (lane == 0) {
        int c = (int)(best & 8191u);
        idxOut[gw] = c;
        out4[gw] = (float)c;
    }
}

// ---------------- Kernel C: gather + outputs + per-row loss partial ----------------
__global__ void vq_gather_kernel(const float* __restrict__ x,
                                 const float* __restrict__ cb,
                                 const int* __restrict__ idxArr,
                                 float* __restrict__ out0,
                                 float* __restrict__ out3,
                                 float* __restrict__ rowPart) {
    int gw = (blockIdx.x * blockDim.x + threadIdx.x) >> 6;
    int lane = threadIdx.x & 63;
    if (gw >= N_ROWS) return;
    int idx = idxArr[gw];
    const float2* xp = (const float2*)(x  + (size_t)gw * DIM);
    const float2* qp = (const float2*)(cb + (size_t)idx * DIM);
    float2* o0 = (float2*)(out0 + (size_t)gw * DIM);
    float2* o3 = (float2*)(out3 + (size_t)gw * DIM);
    float part = 0.0f;
    #pragma unroll
    for (int r = 0; r < 4; ++r) {
        int e = r * 64 + lane;
        float2 xv = xp[e];
        float2 qv = qp[e];
        float dx = qv.x - xv.x, dy = qv.y - xv.y;
        part += dx * dx + dy * dy;
        float2 o; o.x = xv.x + dx; o.y = xv.y + dy;
        o0[e] = o;
        o3[e] = qv;
    }
    #pragma unroll
    for (int m = 32; m; m >>= 1) part += __shfl_xor(part, m);
    if (lane == 0) rowPart[gw] = part;
}

// ---------------- Kernel D: deterministic loss reduce ----------------
__global__ void vq_loss_kernel(const float* __restrict__ rowPart,
                               float* __restrict__ out1, float* __restrict__ out2) {
    __shared__ float red[256];
    int t = threadIdx.x;
    float s = 0.0f;
    for (int r = t; r < N_ROWS; r += 256) s += rowPart[r];
    red[t] = s;
    __syncthreads();
    #pragma unroll
    for (int m = 128; m; m >>= 1) {
        if (t < m) red[t] += red[t + m];
        __syncthreads();
    }
    if (t == 0) {
        float loss = red[0] / (float)(N_ROWS * DIM);
        out1[0] = loss;
        out2[0] = loss;
    }
}

extern "C" void kernel_launch(void* const* d_in, const int* in_sizes, int n_in,
                              void* d_out, int out_size, void* d_ws, size_t ws_size,
                              hipStream_t stream) {
    const float* x  = (const float*)d_in[0];   // [16384, 512]
    const float* cb = (const float*)d_in[1];   // [8192, 512]
    float* out  = (float*)d_out;
    float* out0 = out;                         // quantized_out [8388608]
    float* out1 = out + 8388608;               // q_latent_loss [1]
    float* out2 = out + 8388609;               // e_latent_loss [1]
    float* out3 = out + 8388610;               // quantized [8388608]
    float* out4 = out + 16777218;              // idx as float [16384]

    // d_out scratch (stream-ordered; consumed before gather overwrites):
    // xf8 8.4MB + cf8 4.2MB in out0 region; top3 (64*16384*3 u64 = 25MB) in out3 region.
    u32* xf8   = (u32*)out0;                   // [0, 2097152) floats
    u32* cf8   = (u32*)(out + 2097152);        // [2097152, 3145728)
    u64* wsTop3 = (u64*)(out + 8388612);       // [8388612, 14680068)  8B-aligned

    char* ws = (char*)d_ws;
    float* wsA    = (float*)ws;                // 16384 f
    float* wsB    = (float*)(ws + 65536);      // 8192 f
    int*   wsIdx  = (int*)(ws + 98304);        // 16384 int
    float* wsPart = (float*)(ws + 163840);     // 16384 f

    hipLaunchKernelGGL(vq_split_kernel,   dim3(12288), dim3(256), 0, stream,
                       x, cb, xf8, cf8);
    hipLaunchKernelGGL(vq_np_norm_kernel, dim3(3072), dim3(256), 0, stream, x, cb, wsA, wsB);
    hipLaunchKernelGGL(vq_screen_kernel,  dim3(N_ROWS / BMR, CHUNKS), dim3(256), 0, stream,
                       (const u8*)xf8, (const u8*)cf8, wsTop3);
    hipLaunchKernelGGL(vq_refine_kernel,  dim3(4096), dim3(256), 0, stream,
                       x, cb, wsA, wsB, wsTop3, wsIdx, out4);
    hipLaunchKernelGGL(vq_gather_kernel,  dim3(4096), dim3(256), 0, stream,
                       x, cb, wsIdx, out0, out3, wsPart);
    hipLaunchKernelGGL(vq_loss_kernel,    dim3(1),    dim3(256), 0, stream,
                       wsPart, out1, out2);
}

// Round 23
// 203.808 us; speedup vs baseline: 3.0569x; 1.0019x over previous
//
#include <hip/hip_runtime.h>

typedef unsigned long long u64;
typedef unsigned int u32;
typedef unsigned short u16;
typedef unsigned char u8;

#define N_ROWS 16384
#define DIM    512
#define K_CODES 8192

#define CHUNKS 64
#define CHUNK_CODES 128
#define BMR 128
#define KC 64                 // fp8 k-elems per tile
#define KTILES (DIM / KC)     // 8

typedef int   i32x4  __attribute__((ext_vector_type(4)));
typedef int   i32x8  __attribute__((ext_vector_type(8)));
typedef float f32x16 __attribute__((ext_vector_type(16)));

// sorted ascending 3-slot insert (r14-verified)
__device__ __forceinline__ void t3_insert(u64* a, u64 k) {
    u64 x = k;
    bool l0 = x < a[0]; u64 n0 = l0 ? x : a[0]; x = l0 ? a[0] : x;
    bool l1 = x < a[1]; u64 n1 = l1 ? x : a[1]; x = l1 ? a[1] : x;
    bool l2 = x < a[2]; u64 n2 = l2 ? x : a[2];
    a[0] = n0; a[1] = n1; a[2] = n2;
}

// ---------------- Kernel P: fp8 e4m3 split; cb pre-scaled by 2^13 (verified r22) ----
__global__ void vq_split_kernel(const float* __restrict__ x, const float* __restrict__ cb,
                                u32* __restrict__ xf8, u32* __restrict__ cf8) {
    size_t t = (size_t)blockIdx.x * blockDim.x + threadIdx.x;
    const size_t nx = (size_t)N_ROWS * DIM / 4;
    const size_t nc = (size_t)K_CODES * DIM / 4;
    if (t < nx) {
        float4 v = ((const float4*)x)[t];
        u32 r = (u32)__builtin_amdgcn_cvt_pk_fp8_f32(v.x, v.y, 0, false);
        r = (u32)__builtin_amdgcn_cvt_pk_fp8_f32(v.z, v.w, (int)r, true);
        xf8[t] = r;
    } else if (t < nx + nc) {
        float4 v = ((const float4*)cb)[t - nx];
        u32 r = (u32)__builtin_amdgcn_cvt_pk_fp8_f32(v.x * 8192.0f, v.y * 8192.0f, 0, false);
        r = (u32)__builtin_amdgcn_cvt_pk_fp8_f32(v.z * 8192.0f, v.w * 8192.0f, (int)r, true);
        cf8[t - nx] = r;
    }
}

// ---------------- Kernel N: numpy-pairwise fp32 row norms, wave-parallel (verified r18) ----
__global__ void vq_np_norm_kernel(const float* __restrict__ x, const float* __restrict__ cb,
                                  float* __restrict__ Arow, float* __restrict__ Bcode) {
    int wid = (blockIdx.x * blockDim.x + threadIdx.x) >> 6;
    int lane = threadIdx.x & 63;
    int r2 = lane >> 5;
    int b  = (lane >> 3) & 3;
    int j  = lane & 7;
    int row = wid * 2 + r2;
    const float* p;
    float* o;
    if (row < N_ROWS) { p = x + (size_t)row * DIM; o = Arow + row; }
    else              { int c = row - N_ROWS; p = cb + (size_t)c * DIM; o = Bcode + c; }
    const float* q = p + b * 128 + j;
    float v0 = q[0];
    float s = __fmul_rn(v0, v0);
    #pragma unroll
    for (int i = 1; i < 16; ++i) {
        float v = q[8 * i];
        s = __fadd_rn(s, __fmul_rn(v, v));
    }
    s = __fadd_rn(s, __shfl_xor(s, 1));
    s = __fadd_rn(s, __shfl_xor(s, 2));
    s = __fadd_rn(s, __shfl_xor(s, 4));
    s = __fadd_rn(s, __shfl_xor(s, 8));
    s = __fadd_rn(s, __shfl_xor(s, 16));
    if ((lane & 31) == 0) *o = s;
}

// ---------------- Kernel S: fp8 MFMA screen, ONE barrier per kt ------------------
// r22 geometry/numerics; schedule: {vmcnt(4); barrier; stage(kt+2); reads; MFMA}.
// Entry barrier of kt proves all waves consumed buf(kt-1) (their kt-1 ds_reads are
// lgkm-drained by kt-1's MFMAs, which precede this barrier) -> stage(kt+2) into
// buf (kt-1)%3 after the barrier is WAR-safe. vmcnt(4) drains exactly stage(kt).
// Fragments loaded as two direct b128s into i32x8 halves (no scalar assembly).
__launch_bounds__(256, 3)
__global__ void vq_screen_kernel(const u8* __restrict__ xf8, const u8* __restrict__ cf8,
                                 u64* __restrict__ top3out) {
    __shared__ __align__(16) u8 lds[3][16384];   // X[128][64] @0 | C[128][64] @8192

    const int t = threadIdx.x;
    const int lane = t & 63;
    const int w = t >> 6;        // 0..3
    const int wrow  = w >> 1;    // 0..1 -> x-rows [64*wrow, +64)
    const int wcode = w & 1;     // 0..1 -> codes  [64*wcode, +64)
    const int l31 = lane & 31;
    const int h = lane >> 5;     // k-half selector

    const int rowBase   = blockIdx.x * BMR;
    const int chunkBase = blockIdx.y * CHUNK_CODES;

    // staging: 16 segs of 1KB (16 rows x 64B); pre-swizzled source chunk
    const size_t laneOff = (size_t)(lane >> 2) * DIM
                         + (size_t)(((lane & 3) ^ ((lane >> 3) & 3)) * 16);
    const u8* srcs[4];
    int dsts[4];
    #pragma unroll
    for (int j = 0; j < 4; ++j) {
        int q = j * 4 + w;
        const u8* gp = (q < 8) ? (xf8 + (size_t)(rowBase + q * 16) * DIM)
                               : (cf8 + (size_t)(chunkBase + (q - 8) * 16) * DIM);
        srcs[j] = gp + laneOff;
        dsts[j] = q * 1024;
    }

    auto stage = [&](int kt) {
        u8* B = &lds[kt % 3][0];
        #pragma unroll
        for (int j = 0; j < 4; ++j) {
            __builtin_amdgcn_global_load_lds(
                (const __attribute__((address_space(1))) u32*)(srcs[j] + kt * KC),
                (__attribute__((address_space(3))) u32*)(B + dsts[j]),
                16, 0, 0);
        }
    };

    // fragment LDS byte offsets (kt-invariant); slot = (h*2+b) ^ ((row>>1)&3)
    const int swz = (l31 >> 1) & 3;
    const int s0 = ((h * 2 + 0) ^ swz) * 16;
    const int s1 = ((h * 2 + 1) ^ swz) * 16;
    int aOff0[2], aOff1[2], bOff0[2], bOff1[2];
    #pragma unroll
    for (int mi = 0; mi < 2; ++mi) {
        int rc = wcode * 64 + mi * 32 + l31;
        aOff0[mi] = 8192 + rc * 64 + s0;
        aOff1[mi] = 8192 + rc * 64 + s1;
    }
    #pragma unroll
    for (int ni = 0; ni < 2; ++ni) {
        int rx = wrow * 64 + ni * 32 + l31;
        bOff0[ni] = rx * 64 + s0;
        bOff1[ni] = rx * 64 + s1;
    }

    f32x16 acc[2][2] = {};

    stage(0);
    stage(1);

    #pragma unroll
    for (int kt = 0; kt < KTILES; ++kt) {
        if (kt + 1 < KTILES) {
            asm volatile("s_waitcnt vmcnt(4)" ::: "memory");   // stage(kt) complete
        } else {
            asm volatile("s_waitcnt vmcnt(0)" ::: "memory");
        }
        asm volatile("s_barrier" ::: "memory");
        if (kt + 2 < KTILES) stage(kt + 2);

        const u8* L = &lds[kt % 3][0];
        i32x8 Af[2], Bf[2];
        #pragma unroll
        for (int mi = 0; mi < 2; ++mi) {
            *(i32x4*)&Af[mi]       = *(const i32x4*)(L + aOff0[mi]);
            *((i32x4*)&Af[mi] + 1) = *(const i32x4*)(L + aOff1[mi]);
        }
        #pragma unroll
        for (int ni = 0; ni < 2; ++ni) {
            *(i32x4*)&Bf[ni]       = *(const i32x4*)(L + bOff0[ni]);
            *((i32x4*)&Bf[ni] + 1) = *(const i32x4*)(L + bOff1[ni]);
        }
        __builtin_amdgcn_s_setprio(1);
        #pragma unroll
        for (int ni = 0; ni < 2; ++ni)
            #pragma unroll
            for (int mi = 0; mi < 2; ++mi)
                acc[mi][ni] = __builtin_amdgcn_mfma_scale_f32_32x32x64_f8f6f4(
                    Af[mi], Bf[ni], acc[mi][ni], 0, 0, 0, 127, 0, 127);
        __builtin_amdgcn_s_setprio(0);
    }

    // ---- fold: 32x32 C layout (col=lane&31=xrow; code=(reg&3)+8*(reg>>2)+4*h) ----
    __syncthreads();
    u64* t3buf = (u64*)&lds[0][0];   // [128 rows][2 wcode][3 slots] = 6KB

    #pragma unroll
    for (int ni = 0; ni < 2; ++ni) {
        float v0 = -3.4e38f, v1 = -3.4e38f, v2 = -3.4e38f;
        int   i0 = 0, i1 = 0, i2 = 0;
        #pragma unroll
        for (int mi = 0; mi < 2; ++mi) {
            const int cb0 = chunkBase + wcode * 64 + mi * 32 + 4 * h;
            #pragma unroll
            for (int reg = 0; reg < 16; ++reg) {
                float v = acc[mi][ni][reg];
                int idx = cb0 + (reg & 3) + 8 * (reg >> 2);
                bool c0 = v > v0, c1 = v > v1, c2 = v > v2;
                v2 = c1 ? v1 : (c2 ? v : v2); i2 = c1 ? i1 : (c2 ? idx : i2);
                v1 = c0 ? v0 : (c1 ? v : v1); i1 = c0 ? i0 : (c1 ? idx : i1);
                v0 = c0 ? v  : v0;            i0 = c0 ? idx : i0;
            }
        }
        // merge with lane^32 (same xrow, complementary codes)
        float w0 = __shfl_xor(v0, 32), w1 = __shfl_xor(v1, 32), w2 = __shfl_xor(v2, 32);
        int   j0 = __shfl_xor(i0, 32), j1 = __shfl_xor(i1, 32), j2 = __shfl_xor(i2, 32);
        #pragma unroll
        for (int s = 0; s < 3; ++s) {
            float ov = (s == 0) ? w0 : (s == 1) ? w1 : w2;
            int   oi = (s == 0) ? j0 : (s == 1) ? j1 : j2;
            bool c0 = ov > v0, c1 = ov > v1, c2 = ov > v2;
            v2 = c1 ? v1 : (c2 ? ov : v2); i2 = c1 ? i1 : (c2 ? oi : i2);
            v1 = c0 ? v0 : (c1 ? ov : v1); i1 = c0 ? i0 : (c1 ? oi : i1);
            v0 = c0 ? ov : v0;             i0 = c0 ? oi  : i0;
        }
        if (h == 0) {
            int xrl = wrow * 64 + ni * 32 + l31;
            u32 b0 = __float_as_uint(v0);
            u32 k0 = (v0 < 0.0f) ? b0 : (~b0 & 0x7FFFFFFFu);
            u32 b1 = __float_as_uint(v1);
            u32 k1 = (v1 < 0.0f) ? b1 : (~b1 & 0x7FFFFFFFu);
            u32 b2 = __float_as_uint(v2);
            u32 k2 = (v2 < 0.0f) ? b2 : (~b2 & 0x7FFFFFFFu);
            t3buf[(xrl * 2 + wcode) * 3 + 0] = ((u64)k0 << 13) | (u32)i0;
            t3buf[(xrl * 2 + wcode) * 3 + 1] = ((u64)k1 << 13) | (u32)i1;
            t3buf[(xrl * 2 + wcode) * 3 + 2] = ((u64)k2 << 13) | (u32)i2;
        }
    }
    __syncthreads();
    if (t < BMR) {
        u64 best[3];
        best[0] = t3buf[(t * 2 + 0) * 3 + 0];
        best[1] = t3buf[(t * 2 + 0) * 3 + 1];
        best[2] = t3buf[(t * 2 + 0) * 3 + 2];
        t3_insert(best, t3buf[(t * 2 + 1) * 3 + 0]);
        t3_insert(best, t3buf[(t * 2 + 1) * 3 + 1]);
        t3_insert(best, t3buf[(t * 2 + 1) * 3 + 2]);
        size_t o = ((size_t)blockIdx.y * N_ROWS + rowBase + t) * 3;
        top3out[o + 0] = best[0];
        top3out[o + 1] = best[1];
        top3out[o + 2] = best[2];
    }
}

// ---------------- Kernel R: global top-8 of 64x3 keys -> exact np re-decision (r14) ---
__global__ void vq_refine_kernel(const float* __restrict__ x, const float* __restrict__ cb,
                                 const float* __restrict__ Arow, const float* __restrict__ Bcode,
                                 const u64* __restrict__ top3, int* __restrict__ idxOut,
                                 float* __restrict__ out4) {
    int gw = (blockIdx.x * blockDim.x + threadIdx.x) >> 6;
    int lane = threadIdx.x & 63;
    if (gw >= N_ROWS) return;

    const u64* tp = top3 + ((size_t)lane * N_ROWS + gw) * 3;
    u64 a0 = tp[0], a1 = tp[1], a2 = tp[2];

    u64 cand[8];
    #pragma unroll
    for (int j = 0; j < 8; ++j) {
        u64 m = a0;
        #pragma unroll
        for (int s = 1; s < 64; s <<= 1) { u64 o = __shfl_xor(m, s); m = o < m ? o : m; }
        cand[j] = m;
        if (a0 == m) { a0 = a1; a1 = a2; a2 = ~0ull; }
    }

    float Ai = Arow[gw];
    const float* xr = x + (size_t)gw * DIM;
    float xv[8];
    #pragma unroll
    for (int e = 0; e < 8; ++e) xv[e] = xr[e * 64 + lane];

    u64 best = ~0ull;
    #pragma unroll
    for (int j = 0; j < 8; ++j) {
        int c = (int)(cand[j] & 8191u);
        const float* er = cb + (size_t)c * DIM;
        double d = 0.0;
        #pragma unroll
        for (int e = 0; e < 8; ++e)
            d = fma((double)xv[e], (double)er[e * 64 + lane], d);
        #pragma unroll
        for (int m = 1; m < 64; m <<= 1) d += __shfl_xor(d, m);
        float m32 = (float)d;
        float dist = __fsub_rn(__fadd_rn(Ai, Bcode[c]), 2.0f * m32);
        u64 ek = ((u64)__float_as_uint(dist) << 13) | (u64)(u32)c;
        best = ek < best ? ek : best;
    }
    if (lane == 0) {
        int c = (int)(best & 8191u);
        idxOut[gw] = c;
        out4[gw] = (float)c;
    }
}

// ---------------- Kernel C: gather + outputs + per-row loss partial ----------------
__global__ void vq_gather_kernel(const float* __restrict__ x,
                                 const float* __restrict__ cb,
                                 const int* __restrict__ idxArr,
                                 float* __restrict__ out0,
                                 float* __restrict__ out3,
                                 float* __restrict__ rowPart) {
    int gw = (blockIdx.x * blockDim.x + threadIdx.x) >> 6;
    int lane = threadIdx.x & 63;
    if (gw >= N_ROWS) return;
    int idx = idxArr[gw];
    const float2* xp = (const float2*)(x  + (size_t)gw * DIM);
    const float2* qp = (const float2*)(cb + (size_t)idx * DIM);
    float2* o0 = (float2*)(out0 + (size_t)gw * DIM);
    float2* o3 = (float2*)(out3 + (size_t)gw * DIM);
    float part = 0.0f;
    #pragma unroll
    for (int r = 0; r < 4; ++r) {
        int e = r * 64 + lane;
        float2 xv = xp[e];
        float2 qv = qp[e];
        float dx = qv.x - xv.x, dy = qv.y - xv.y;
        part += dx * dx + dy * dy;
        float2 o; o.x = xv.x + dx; o.y = xv.y + dy;
        o0[e] = o;
        o3[e] = qv;
    }
    #pragma unroll
    for (int m = 32; m; m >>= 1) part += __shfl_xor(part, m);
    if (lane == 0) rowPart[gw] = part;
}

// ---------------- Kernel D: deterministic loss reduce ----------------
__global__ void vq_loss_kernel(const float* __restrict__ rowPart,
                               float* __restrict__ out1, float* __restrict__ out2) {
    __shared__ float red[256];
    int t = threadIdx.x;
    float s = 0.0f;
    for (int r = t; r < N_ROWS; r += 256) s += rowPart[r];
    red[t] = s;
    __syncthreads();
    #pragma unroll
    for (int m = 128; m; m >>= 1) {
        if (t < m) red[t] += red[t + m];
        __syncthreads();
    }
    if (t == 0) {
        float loss = red[0] / (float)(N_ROWS * DIM);
        out1[0] = loss;
        out2[0] = loss;
    }
}

extern "C" void kernel_launch(void* const* d_in, const int* in_sizes, int n_in,
                              void* d_out, int out_size, void* d_ws, size_t ws_size,
                              hipStream_t stream) {
    const float* x  = (const float*)d_in[0];   // [16384, 512]
    const float* cb = (const float*)d_in[1];   // [8192, 512]
    float* out  = (float*)d_out;
    float* out0 = out;                         // quantized_out [8388608]
    float* out1 = out + 8388608;               // q_latent_loss [1]
    float* out2 = out + 8388609;               // e_latent_loss [1]
    float* out3 = out + 8388610;               // quantized [8388608]
    float* out4 = out + 16777218;              // idx as float [16384]

    // d_out scratch (stream-ordered; consumed before gather overwrites):
    // xf8 8.4MB + cf8 4.2MB in out0 region; top3 (64*16384*3 u64 = 25MB) in out3 region.
    u32* xf8   = (u32*)out0;                   // [0, 2097152) floats
    u32* cf8   = (u32*)(out + 2097152);        // [2097152, 3145728)
    u64* wsTop3 = (u64*)(out + 8388612);       // [8388612, 14680068)  8B-aligned

    char* ws = (char*)d_ws;
    float* wsA    = (float*)ws;                // 16384 f
    float* wsB    = (float*)(ws + 65536);      // 8192 f
    int*   wsIdx  = (int*)(ws + 98304);        // 16384 int
    float* wsPart = (float*)(ws + 163840);     // 16384 f

    hipLaunchKernelGGL(vq_split_kernel,   dim3(12288), dim3(256), 0, stream,
                       x, cb, xf8, cf8);
    hipLaunchKernelGGL(vq_np_norm_kernel, dim3(3072), dim3(256), 0, stream, x, cb, wsA, wsB);
    hipLaunchKernelGGL(vq_screen_kernel,  dim3(N_ROWS / BMR, CHUNKS), dim3(256), 0, stream,
                       (const u8*)xf8, (const u8*)cf8, wsTop3);
    hipLaunchKernelGGL(vq_refine_kernel,  dim3(4096), dim3(256), 0, stream,
                       x, cb, wsA, wsB, wsTop3, wsIdx, out4);
    hipLaunchKernelGGL(vq_gather_kernel,  dim3(4096), dim3(256), 0, stream,
                       x, cb, wsIdx, out0, out3, wsPart);
    hipLaunchKernelGGL(vq_loss_kernel,    dim3(1),    dim3(256), 0, stream,
                       wsPart, out1, out2);
}